// Round 12
// baseline (797.853 us; speedup 1.0000x reference)
//
#include <hip/hip_runtime.h>
#include <hip/hip_fp16.h>
#include <cstdint>

typedef _Float16 h16;
typedef _Float16 half8 __attribute__((ext_vector_type(8)));
typedef float floatx4 __attribute__((ext_vector_type(4)));

#define T_SZ 60
#define H_SZ 128
#define NB_FC1 7680   // T*H = 60*128

#define LOG2E  1.44269504088896340736f
#define LOG2E2 2.88539008177792681472f

__device__ __forceinline__ float sigm(float x) {
    float e = __builtin_amdgcn_exp2f(x * -LOG2E);
    return __builtin_amdgcn_rcpf(1.0f + e);
}
__device__ __forceinline__ float tanh_fast(float x) {
    float e = __builtin_amdgcn_exp2f(x * LOG2E2);   // exp(2x)
    return 1.0f - 2.0f * __builtin_amdgcn_rcpf(e + 1.0f);
}

// ---------------------------------------------------------------------------
// FUSED two-layer LSTM: one kernel, 61 barrier-iterations u=0..60 running
// {L1 step u  ||  L2 step u-1} per iteration. The layers' chains are
// independent within an iteration (L2 consumes h1(u-1), published one
// barrier earlier), so per-wave independent work doubles with zero extra
// MFMAs, wall steps halve (61 vs 120), and h1 NEVER goes to HBM (16-slot
// LDS ring only; saves a 126 MB round-trip).
// Shared read: L1's h-fragments and L2's x-fragments are BOTH h1(u-1) --
// one set of 4 ds_read_b128 feeds both MFMA groups.
// block = 16 batch rows, grid 256, 512 threads (8 waves, 1 block/CU).
// Wave w owns gate n-tiles {w,8+w,16+w,24+w} of BOTH layers; cell updates
// are pure per-lane register math. Weights: 224 regs/wave -> MFMA AV
// register classes let the allocator park them in AGPRs (512 unified budget).
// h2 in a 16-slot ring, flushed every 8 steps with wide coalesced stores.
// 1 raw barrier per iteration (lgkmcnt-only wait; global loads in flight).
// ---------------------------------------------------------------------------
__global__ __launch_bounds__(512, 1)
void lstm_fused(const float* __restrict__ X,
                const float* __restrict__ W_ih1, const float* __restrict__ W_hh1,
                const float* __restrict__ b_ih1, const float* __restrict__ b_hh1,
                const float* __restrict__ W_ih2, const float* __restrict__ W_hh2,
                const float* __restrict__ b_ih2, const float* __restrict__ b_hh2,
                h16* __restrict__ h2_out)
{
    __shared__ __align__(16) h16 ring1[16][16][H_SZ];   // 64 KB, h1 history
    __shared__ __align__(16) h16 ring2[16][16][H_SZ];   // 64 KB, h2 history

    const int tid  = threadIdx.x;
    const int w    = tid >> 6;
    const int lane = tid & 63;
    const int lrow = lane & 15;   // A-row / B-col within tile
    const int lgrp = lane >> 4;   // k-group
    const size_t base_row = (size_t)blockIdx.x * 16;

    // -------- register-resident weight fragments for BOTH layers ------------
    half8 wf1_in[4][2], wf1_hh[4][4], wf2_in[4][4], wf2_hh[4][4];
    float bias1[4], bias2[4];

    #pragma unroll
    for (int q = 0; q < 4; ++q) {
        const int n = (w + 8 * q) * 16 + lrow;      // gate row (0..511)
        bias1[q] = b_ih1[n] + b_hh1[n];
        bias2[q] = b_ih2[n] + b_hh2[n];
        #pragma unroll
        for (int kt = 0; kt < 2; ++kt) {
            const float* p = W_ih1 + (size_t)n * 64 + kt * 32 + lgrp * 8;
            half8 v;
            #pragma unroll
            for (int j = 0; j < 8; ++j) v[j] = (h16)p[j];
            wf1_in[q][kt] = v;
        }
        #pragma unroll
        for (int kt = 0; kt < 4; ++kt) {
            const float* p = W_hh1 + (size_t)n * H_SZ + kt * 32 + lgrp * 8;
            half8 v;
            #pragma unroll
            for (int j = 0; j < 8; ++j) v[j] = (h16)p[j];
            wf1_hh[q][kt] = v;
        }
        #pragma unroll
        for (int kt = 0; kt < 4; ++kt) {
            const float* p = W_ih2 + (size_t)n * H_SZ + kt * 32 + lgrp * 8;
            half8 v;
            #pragma unroll
            for (int j = 0; j < 8; ++j) v[j] = (h16)p[j];
            wf2_in[q][kt] = v;
        }
        #pragma unroll
        for (int kt = 0; kt < 4; ++kt) {
            const float* p = W_hh2 + (size_t)n * H_SZ + kt * 32 + lgrp * 8;
            half8 v;
            #pragma unroll
            for (int j = 0; j < 8; ++j) v[j] = (h16)p[j];
            wf2_hh[q][kt] = v;
        }
    }

    // x prefetch: two slots (distance 2), f32 raw, pkrtz cvt at consume
    floatx4 rA[2][2], rB[2][2];

    auto load_x = [&](int t, floatx4 (&raw)[2][2]) {
        #pragma unroll
        for (int kt = 0; kt < 2; ++kt) {
            const float* p = X + ((base_row + lrow) * T_SZ + t) * 64 + kt * 32 + lgrp * 8;
            raw[kt][0] = *(const floatx4*)(p);
            raw[kt][1] = *(const floatx4*)(p + 4);
        }
    };
    auto get_x = [&](const floatx4 (&raw)[2][2], half8 (&xf)[2]) {
        #pragma unroll
        for (int kt = 0; kt < 2; ++kt) {
            const auto p0 = __builtin_amdgcn_cvt_pkrtz(raw[kt][0][0], raw[kt][0][1]);
            const auto p1 = __builtin_amdgcn_cvt_pkrtz(raw[kt][0][2], raw[kt][0][3]);
            const auto p2 = __builtin_amdgcn_cvt_pkrtz(raw[kt][1][0], raw[kt][1][1]);
            const auto p3 = __builtin_amdgcn_cvt_pkrtz(raw[kt][1][2], raw[kt][1][3]);
            half8 v;
            v[0] = (h16)p0[0]; v[1] = (h16)p0[1]; v[2] = (h16)p1[0]; v[3] = (h16)p1[1];
            v[4] = (h16)p2[0]; v[5] = (h16)p2[1]; v[6] = (h16)p3[0]; v[7] = (h16)p3[1];
            xf[kt] = v;
        }
    };

    floatx4 c1 = {0.f, 0.f, 0.f, 0.f};
    floatx4 c2 = {0.f, 0.f, 0.f, 0.f};
    const int colW = 16 * w + lrow;

    auto flush2 = [&](int s) {   // stores h2(s-7..s); slots disjoint from next 8 writes
        half8 vals[4];
        int   time[4], row[4], cg[4];
        #pragma unroll
        for (int k = 0; k < 4; ++k) {
            const int u = tid + 512 * k;        // 0..2047
            time[k] = s - 7 + (u >> 8);
            row[k]  = (u >> 4) & 15;
            cg[k]   = u & 15;
            vals[k] = *(const half8*)&ring2[time[k] & 15][row[k]][(cg[k] * 8) ^ ((row[k] & 7) << 3)];
        }
        #pragma unroll
        for (int k = 0; k < 4; ++k)
            *(half8*)(h2_out + ((base_row + row[k]) * T_SZ + time[k]) * H_SZ + cg[k] * 8) = vals[k];
    };

    load_x(0, rA);
    load_x(1, rB);

    auto iter = [&](int u, floatx4 (&rawC)[2][2]) {
        // ---- shared LDS fragment reads, issued first ----------------------
        half8 hA[4];    // h1(u-1): A-operand for L1 h-MFMAs AND L2 x-MFMAs
        half8 hf2[4];   // h2(u-2): A-operand for L2 h-MFMAs
        if (u >= 1) {
            const h16* p1 = &ring1[(u - 1) & 15][0][0];
            #pragma unroll
            for (int kt = 0; kt < 4; ++kt) {
                const int col0 = kt * 32 + lgrp * 8;
                hA[kt] = *(const half8*)(p1 + lrow * H_SZ + (col0 ^ ((lrow & 7) << 3)));
            }
            if (u >= 2) {
                const h16* p2 = &ring2[(u - 2) & 15][0][0];
                #pragma unroll
                for (int kt = 0; kt < 4; ++kt) {
                    const int col0 = kt * 32 + lgrp * 8;
                    hf2[kt] = *(const half8*)(p2 + lrow * H_SZ + (col0 ^ ((lrow & 7) << 3)));
                }
            }
        }

        // ---- L1: step u ---------------------------------------------------
        if (u < T_SZ) {
            half8 xf[2];
            get_x(rawC, xf);
            floatx4 acc1[4];
            #pragma unroll
            for (int q = 0; q < 4; ++q) acc1[q] = floatx4{bias1[q], bias1[q], bias1[q], bias1[q]};
            #pragma unroll
            for (int kt = 0; kt < 2; ++kt)
                #pragma unroll
                for (int q = 0; q < 4; ++q)
                    acc1[q] = __builtin_amdgcn_mfma_f32_16x16x32_f16(xf[kt], wf1_in[q][kt], acc1[q], 0, 0, 0);
            if (u + 2 < T_SZ) load_x(u + 2, rawC);
            if (u >= 1) {
                #pragma unroll
                for (int kt = 0; kt < 4; ++kt)
                    #pragma unroll
                    for (int q = 0; q < 4; ++q)
                        acc1[q] = __builtin_amdgcn_mfma_f32_16x16x32_f16(hA[kt], wf1_hh[q][kt], acc1[q], 0, 0, 0);
            }
            h16 hc[4];
            #pragma unroll
            for (int r = 0; r < 4; ++r) {
                const float gi = sigm(acc1[0][r]);
                const float gf = sigm(acc1[1][r]);
                const float gg = tanh_fast(acc1[2][r]);
                const float go = sigm(acc1[3][r]);
                const float cc = gf * c1[r] + gi * gg;
                c1[r] = cc;
                hc[r] = (h16)(go * tanh_fast(cc));
            }
            h16* hb = &ring1[u & 15][0][0];
            #pragma unroll
            for (int r = 0; r < 4; ++r) {
                const int rowW = lgrp * 4 + r;
                hb[rowW * H_SZ + (colW ^ ((rowW & 7) << 3))] = hc[r];
            }
        }

        // ---- L2: step s = u-1 ---------------------------------------------
        if (u >= 1) {
            floatx4 acc2[4];
            #pragma unroll
            for (int q = 0; q < 4; ++q) acc2[q] = floatx4{bias2[q], bias2[q], bias2[q], bias2[q]};
            #pragma unroll
            for (int kt = 0; kt < 4; ++kt)
                #pragma unroll
                for (int q = 0; q < 4; ++q)
                    acc2[q] = __builtin_amdgcn_mfma_f32_16x16x32_f16(hA[kt], wf2_in[q][kt], acc2[q], 0, 0, 0);
            if (u >= 2) {
                #pragma unroll
                for (int kt = 0; kt < 4; ++kt)
                    #pragma unroll
                    for (int q = 0; q < 4; ++q)
                        acc2[q] = __builtin_amdgcn_mfma_f32_16x16x32_f16(hf2[kt], wf2_hh[q][kt], acc2[q], 0, 0, 0);
            }
            h16 hc2[4];
            #pragma unroll
            for (int r = 0; r < 4; ++r) {
                const float gi = sigm(acc2[0][r]);
                const float gf = sigm(acc2[1][r]);
                const float gg = tanh_fast(acc2[2][r]);
                const float go = sigm(acc2[3][r]);
                const float cc = gf * c2[r] + gi * gg;
                c2[r] = cc;
                hc2[r] = (h16)(go * tanh_fast(cc));
            }
            h16* hb2 = &ring2[(u - 1) & 15][0][0];
            #pragma unroll
            for (int r = 0; r < 4; ++r) {
                const int rowW = lgrp * 4 + r;
                hb2[rowW * H_SZ + (colW ^ ((rowW & 7) << 3))] = hc2[r];
            }
        }

        // ---- one raw barrier per iteration --------------------------------
        asm volatile("s_waitcnt lgkmcnt(0)" ::: "memory");
        __builtin_amdgcn_s_barrier();
        asm volatile("" ::: "memory");

        if (u >= 1) {
            const int s = u - 1;
            if (((s & 7) == 7) || (s == T_SZ - 1)) flush2(s);
        }
    };

    #pragma unroll 1
    for (int uu = 0; uu <= T_SZ; uu += 2) {
        iter(uu, rA);
        if (uu + 1 <= T_SZ) iter(uu + 1, rB);
    }
}

// ---------------------------------------------------------------------------
// Wc = W_fc2 @ W_fc1  ->  [60, 7680] fp16   (folded linear head)
// ---------------------------------------------------------------------------
__global__ __launch_bounds__(256, 2)
void wc_kernel(const float* __restrict__ W_fc1,   // [512][7680]
               const float* __restrict__ W_fc2,   // [60][512]
               h16* __restrict__ Wc)              // [60][7680]
{
    __shared__ __align__(16) float lds1[64 * 16];   // [k][j]
    __shared__ __align__(16) float lds2[64 * 68];   // [k][m] (padded)
    const int tid = threadIdx.x;
    const int j0  = blockIdx.x * 16;
    const int jt  = tid & 15;
    const int mt  = tid >> 4;          // m-set {4mt .. 4mt+3}
    float acc[4] = {0.f, 0.f, 0.f, 0.f};

    for (int kc = 0; kc < 512; kc += 64) {
        __syncthreads();
        for (int i = tid; i < 64 * 16; i += 256) {
            const int k = i >> 4, jj = i & 15;
            lds1[k * 16 + jj] = W_fc1[(size_t)(kc + k) * NB_FC1 + j0 + jj];
        }
        for (int i = tid; i < 64 * 64; i += 256) {
            const int k = i & 63, m = i >> 6;
            lds2[k * 68 + m] = (m < 60) ? W_fc2[m * 512 + kc + k] : 0.f;
        }
        __syncthreads();
        for (int k = 0; k < 64; ++k) {
            const float v1 = lds1[k * 16 + jt];
            const floatx4 v2 = *(const floatx4*)&lds2[k * 68 + 4 * mt];
            acc[0] += v2[0] * v1; acc[1] += v2[1] * v1;
            acc[2] += v2[2] * v1; acc[3] += v2[3] * v1;
        }
    }
    #pragma unroll
    for (int s = 0; s < 4; ++s) {
        const int m = 4 * mt + s;
        if (m < 60) Wc[(size_t)m * NB_FC1 + j0 + jt] = (h16)acc[s];
    }
}

// bc = W_fc2 @ b_fc1 + b_fc2   [60] fp32
__global__ void bc_kernel(const float* __restrict__ W_fc2, const float* __restrict__ b_fc1,
                          const float* __restrict__ b_fc2, float* __restrict__ bc)
{
    const int m = blockIdx.x, t = threadIdx.x;
    float p = W_fc2[m * 512 + t] * b_fc1[t] + W_fc2[m * 512 + 256 + t] * b_fc1[256 + t];
    #pragma unroll
    for (int off = 1; off < 64; off <<= 1) p += __shfl_xor(p, off);
    __shared__ float sred[4];
    if ((t & 63) == 0) sred[t >> 6] = p;
    __syncthreads();
    if (t == 0) bc[m] = sred[0] + sred[1] + sred[2] + sred[3] + b_fc2[m];
}

// ---------------------------------------------------------------------------
// out[B,60] = h2flat[B,7680] @ Wc^T + bc.
// ---------------------------------------------------------------------------
__global__ __launch_bounds__(256, 2)
void fc_kernel(const h16* __restrict__ h2,
               const h16* __restrict__ Wc,
               const float* __restrict__ bcv,
               float* __restrict__ out)
{
    __shared__ float red[4][4][16][16];   // [wave][q][row][col]
    const int tid = threadIdx.x;
    const int w = tid >> 6, lane = tid & 63, lrow = lane & 15, lgrp = lane >> 4;
    const size_t base_row = (size_t)blockIdx.x * 16;

    floatx4 acc[4];
    #pragma unroll
    for (int q = 0; q < 4; ++q) acc[q] = floatx4{0.f, 0.f, 0.f, 0.f};

    const h16* arow = h2 + (base_row + lrow) * NB_FC1;
    for (int i = 0; i < 60; ++i) {
        const int kt = w * 60 + i;
        const int k0 = kt * 32 + lgrp * 8;
        const half8 a = *(const half8*)(arow + k0);
        #pragma unroll
        for (int q = 0; q < 4; ++q) {
            const int n = q * 16 + lrow;
            half8 b = 0;
            if (n < 60) b = *(const half8*)(Wc + (size_t)n * NB_FC1 + k0);
            acc[q] = __builtin_amdgcn_mfma_f32_16x16x32_f16(a, b, acc[q], 0, 0, 0);
        }
    }
    #pragma unroll
    for (int q = 0; q < 4; ++q)
        #pragma unroll
        for (int r = 0; r < 4; ++r)
            red[w][q][lgrp * 4 + r][lrow] = acc[q][r];
    __syncthreads();

    #pragma unroll
    for (int s = 0; s < 4; ++s) {
        const int idx = tid + 256 * s;
        const int row = idx >> 6, col = idx & 63;
        if (col < 60) {
            const int q = col >> 4, cin = col & 15;
            const float v = red[0][q][row][cin] + red[1][q][row][cin]
                          + red[2][q][row][cin] + red[3][q][row][cin];
            out[(base_row + row) * 60 + col] = v + bcv[col];
        }
    }
}

extern "C" void kernel_launch(void* const* d_in, const int* in_sizes, int n_in,
                              void* d_out, int out_size, void* d_ws, size_t ws_size,
                              hipStream_t stream)
{
    const float* X      = (const float*)d_in[0];
    const float* W_ih1  = (const float*)d_in[1];
    const float* W_hh1  = (const float*)d_in[2];
    const float* b_ih1  = (const float*)d_in[3];
    const float* b_hh1  = (const float*)d_in[4];
    const float* W_ih2  = (const float*)d_in[5];
    const float* W_hh2  = (const float*)d_in[6];
    const float* b_ih2  = (const float*)d_in[7];
    const float* b_hh2  = (const float*)d_in[8];
    const float* W_fc1  = (const float*)d_in[9];
    const float* b_fc1  = (const float*)d_in[10];
    const float* W_fc2  = (const float*)d_in[11];
    const float* b_fc2  = (const float*)d_in[12];

    // workspace layout: h2 (63MB fp16) | Wc (0.92MB fp16) | bc
    h16* h2 = (h16*)d_ws;
    h16* Wc = h2 + (size_t)4096 * NB_FC1;
    float* bc = (float*)(Wc + (size_t)60 * NB_FC1);

    wc_kernel<<<480, 256, 0, stream>>>(W_fc1, W_fc2, Wc);
    bc_kernel<<<60, 256, 0, stream>>>(W_fc2, b_fc1, b_fc2, bc);
    lstm_fused<<<256, 512, 0, stream>>>(X, W_ih1, W_hh1, b_ih1, b_hh1,
                                        W_ih2, W_hh2, b_ih2, b_hh2, h2);
    fc_kernel<<<256, 256, 0, stream>>>(h2, Wc, bc, (float*)d_out);
}

// Round 13
// 238.823 us; speedup vs baseline: 3.3408x; 3.3408x over previous
//
#include <hip/hip_runtime.h>
#include <hip/hip_fp16.h>
#include <cstdint>

typedef _Float16 h16;
typedef _Float16 half8 __attribute__((ext_vector_type(8)));
typedef float floatx4 __attribute__((ext_vector_type(4)));

#define T_SZ 60
#define H_SZ 128
#define NB_FC1 7680   // T*H = 60*128

#define LOG2E  1.44269504088896340736f
#define LOG2E2 2.88539008177792681472f

__device__ __forceinline__ float sigm(float x) {
    float e = __builtin_amdgcn_exp2f(x * -LOG2E);
    return __builtin_amdgcn_rcpf(1.0f + e);
}
__device__ __forceinline__ float tanh_fast(float x) {
    float e = __builtin_amdgcn_exp2f(x * LOG2E2);   // exp(2x)
    return 1.0f - 2.0f * __builtin_amdgcn_rcpf(e + 1.0f);
}

// ---------------------------------------------------------------------------
// Fused LSTM layer (proven R10 structure, 99 us/layer):
// block = 16 batch rows x 60 timesteps, grid 256, 512 threads (8 waves,
// 1 block/CU, uncapped 256-reg budget -> no spill).
// Wave w owns gate n-tiles {w, 8+w, 16+w, 24+w} (i,f,g,o for h-cols
// [16w,16w+16)) -> cell update is pure per-lane register math.
// ORDER WITHIN A STEP: issue hf ds_reads -> x-part of t+1 (pkrtz cvt +
// x-MFMAs into accN + load x(t+2)) OVERLAPS the ds_read latency ->
// h-MFMAs(t) -> acts -> ring write -> barrier.
// h history in a 16-slot LDS ring (64KB); flush every 8 steps reads the
// half disjoint from upcoming writes (WAR distance 8 barriers).
// 1 barrier/step, raw s_barrier with lgkmcnt-only wait.
// ---------------------------------------------------------------------------
template<int INDIM, bool IN_F32>
__global__ __launch_bounds__(512, 1)
void lstm_layer(const void* __restrict__ in_v,
                const float* __restrict__ W_ih,
                const float* __restrict__ W_hh,
                const float* __restrict__ b_ih,
                const float* __restrict__ b_hh,
                h16* __restrict__ h_out)
{
    constexpr int KT_IN = INDIM / 32;
    __shared__ __align__(16) h16 hist[16][16][H_SZ];   // 64 KB swizzled ring

    const int tid  = threadIdx.x;
    const int w    = tid >> 6;
    const int lane = tid & 63;
    const int lrow = lane & 15;   // A-row / B-col within tile
    const int lgrp = lane >> 4;   // k-group
    const size_t base_row = (size_t)blockIdx.x * 16;

    // -------- register-resident B-fragments of W_ih / W_hh (fp32 -> fp16) ----
    half8 wf_in[4][KT_IN];
    half8 wf_hh[4][4];
    float bias[4];

    #pragma unroll
    for (int q = 0; q < 4; ++q) {
        const int n = (w + 8 * q) * 16 + lrow;      // gate row (0..511)
        bias[q] = b_ih[n] + b_hh[n];
        #pragma unroll
        for (int kt = 0; kt < KT_IN; ++kt) {
            const float* p = W_ih + (size_t)n * INDIM + kt * 32 + lgrp * 8;
            half8 v;
            #pragma unroll
            for (int j = 0; j < 8; ++j) v[j] = (h16)p[j];   // RN cvt for weights
            wf_in[q][kt] = v;
        }
        #pragma unroll
        for (int kt = 0; kt < 4; ++kt) {
            const float* p = W_hh + (size_t)n * H_SZ + kt * 32 + lgrp * 8;
            half8 v;
            #pragma unroll
            for (int j = 0; j < 8; ++j) v[j] = (h16)p[j];
            wf_hh[q][kt] = v;
        }
    }

    const float* inF = (const float*)in_v;
    const h16*   inH = (const h16*)in_v;

    // single x slot; loaded ~1 full step before consumption
    floatx4 raw[KT_IN][2];
    half8   xs[KT_IN];

    auto load_x = [&](int t) {
        #pragma unroll
        for (int kt = 0; kt < KT_IN; ++kt) {
            if constexpr (IN_F32) {
                const float* p = inF + ((base_row + lrow) * T_SZ + t) * INDIM + kt * 32 + lgrp * 8;
                raw[kt][0] = *(const floatx4*)(p);
                raw[kt][1] = *(const floatx4*)(p + 4);
            } else {
                xs[kt] = *(const half8*)(inH + ((base_row + lrow) * T_SZ + t) * INDIM + kt * 32 + lgrp * 8);
            }
        }
    };

    auto get_x = [&](half8 (&xf)[KT_IN]) {   // consume-point packed cvt (RTZ)
        #pragma unroll
        for (int kt = 0; kt < KT_IN; ++kt) {
            if constexpr (IN_F32) {
                const auto p0 = __builtin_amdgcn_cvt_pkrtz(raw[kt][0][0], raw[kt][0][1]);
                const auto p1 = __builtin_amdgcn_cvt_pkrtz(raw[kt][0][2], raw[kt][0][3]);
                const auto p2 = __builtin_amdgcn_cvt_pkrtz(raw[kt][1][0], raw[kt][1][1]);
                const auto p3 = __builtin_amdgcn_cvt_pkrtz(raw[kt][1][2], raw[kt][1][3]);
                half8 v;
                v[0] = (h16)p0[0]; v[1] = (h16)p0[1]; v[2] = (h16)p1[0]; v[3] = (h16)p1[1];
                v[4] = (h16)p2[0]; v[5] = (h16)p2[1]; v[6] = (h16)p3[0]; v[7] = (h16)p3[1];
                xf[kt] = v;
            } else {
                xf[kt] = xs[kt];
            }
        }
    };

    floatx4 c4 = {0.f, 0.f, 0.f, 0.f};
    const int colW = 16 * w + lrow;   // this lane's h-column

    auto flush = [&](int t) {   // stores h(t-7..t); ring half disjoint from next writes
        half8 vals[4];
        int   time[4], row[4], cg[4];
        #pragma unroll
        for (int s = 0; s < 4; ++s) {
            const int u = tid + 512 * s;        // 0..2047
            time[s] = t - 7 + (u >> 8);
            row[s]  = (u >> 4) & 15;
            cg[s]   = u & 15;
            vals[s] = *(const half8*)&hist[time[s] & 15][row[s]][(cg[s] * 8) ^ ((row[s] & 7) << 3)];
        }
        #pragma unroll
        for (int s = 0; s < 4; ++s)
            *(half8*)(h_out + ((base_row + row[s]) * T_SZ + time[s]) * H_SZ + cg[s] * 8) = vals[s];
    };

    // -------- prologue: accA = bias + x-part(0); prefetch x(1) ---------------
    floatx4 accA[4], accB[4];
    load_x(0);
    {
        half8 xf[KT_IN];
        get_x(xf);
        #pragma unroll
        for (int q = 0; q < 4; ++q) accA[q] = floatx4{bias[q], bias[q], bias[q], bias[q]};
        #pragma unroll
        for (int kt = 0; kt < KT_IN; ++kt)
            #pragma unroll
            for (int q = 0; q < 4; ++q)
                accA[q] = __builtin_amdgcn_mfma_f32_16x16x32_f16(xf[kt], wf_in[q][kt], accA[q], 0, 0, 0);
        load_x(1);
    }

    auto step = [&](int t, floatx4 (&accC)[4], floatx4 (&accN)[4]) {
        // ---- issue hf ds_reads first --------------------------------------
        half8 hf[4];
        const bool have_h = (t > 0);
        if (have_h) {
            const h16* hb = &hist[(t - 1) & 15][0][0];
            #pragma unroll
            for (int kt = 0; kt < 4; ++kt) {
                const int col0 = kt * 32 + lgrp * 8;
                hf[kt] = *(const half8*)(hb + lrow * H_SZ + (col0 ^ ((lrow & 7) << 3)));
            }
        }

        // ---- x-part of step t+1 overlaps the ds_read latency --------------
        if (t + 1 < T_SZ) {
            half8 xf[KT_IN];
            get_x(xf);
            #pragma unroll
            for (int q = 0; q < 4; ++q) accN[q] = floatx4{bias[q], bias[q], bias[q], bias[q]};
            #pragma unroll
            for (int kt = 0; kt < KT_IN; ++kt)
                #pragma unroll
                for (int q = 0; q < 4; ++q)
                    accN[q] = __builtin_amdgcn_mfma_f32_16x16x32_f16(xf[kt], wf_in[q][kt], accN[q], 0, 0, 0);
            if (t + 2 < T_SZ) load_x(t + 2);
        }

        // ---- h-MFMAs on the critical path (accC already holds bias+x(t)) ---
        if (have_h) {
            #pragma unroll
            for (int kt = 0; kt < 4; ++kt)
                #pragma unroll
                for (int q = 0; q < 4; ++q)
                    accC[q] = __builtin_amdgcn_mfma_f32_16x16x32_f16(hf[kt], wf_hh[q][kt], accC[q], 0, 0, 0);
        }

        // ---- activations + cell update + ring write ------------------------
        h16 hcast[4];
        #pragma unroll
        for (int r = 0; r < 4; ++r) {
            const float gi = sigm(accC[0][r]);
            const float gf = sigm(accC[1][r]);
            const float gg = tanh_fast(accC[2][r]);
            const float go = sigm(accC[3][r]);
            const float cc = gf * c4[r] + gi * gg;
            c4[r] = cc;
            hcast[r] = (h16)(go * tanh_fast(cc));
        }
        h16* hb2 = &hist[t & 15][0][0];
        #pragma unroll
        for (int r = 0; r < 4; ++r) {
            const int rowW = lgrp * 4 + r;
            hb2[rowW * H_SZ + (colW ^ ((rowW & 7) << 3))] = hcast[r];
        }

        // raw barrier: wait only on LDS (x loads stay in flight)
        asm volatile("s_waitcnt lgkmcnt(0)" ::: "memory");
        __builtin_amdgcn_s_barrier();
        asm volatile("" ::: "memory");

        if (((t & 7) == 7) || (t == T_SZ - 1)) flush(t);
    };

    #pragma unroll 1
    for (int tt = 0; tt < T_SZ; tt += 2) {
        step(tt,     accA, accB);
        step(tt + 1, accB, accA);
    }
}

// ---------------------------------------------------------------------------
// Wc = W_fc2 @ W_fc1 -> [60, 7680] fp16, MFMA version (no LDS).
// Grid 120 blocks x 4 waves; wave owns 16 output cols (j0). Same fragment
// convention as the verified fc_kernel: A rows = output rows (W_fc2 rows m,
// 8 contiguous k per lane), B slot i <-> k0+i gathered from W_fc1[k][j].
// 64 MFMAs/wave vs the old 1024 ds_read + 2048 scalar FMA per thread.
// ---------------------------------------------------------------------------
__global__ __launch_bounds__(256, 2)
void wc_kernel(const float* __restrict__ W_fc1,   // [512][7680]
               const float* __restrict__ W_fc2,   // [60][512]
               h16* __restrict__ Wc)              // [60][7680]
{
    const int tid  = threadIdx.x;
    const int wv   = tid >> 6;
    const int lane = tid & 63;
    const int lrow = lane & 15;
    const int lgrp = lane >> 4;
    const int j0   = blockIdx.x * 64 + wv * 16;   // this wave's 16 output cols

    floatx4 acc[4];
    #pragma unroll
    for (int mt = 0; mt < 4; ++mt) acc[mt] = floatx4{0.f, 0.f, 0.f, 0.f};

    for (int kt = 0; kt < 16; ++kt) {
        const int k0 = kt * 32 + lgrp * 8;
        // B-frag: slot i = W_fc1[k0+i][j0+lrow] (lanes 0-15 coalesce to 64B)
        half8 bf;
        #pragma unroll
        for (int i = 0; i < 8; ++i)
            bf[i] = (h16)W_fc1[(size_t)(k0 + i) * NB_FC1 + j0 + lrow];
        // A-frags: W_fc2[mt*16+lrow][k0..k0+7] (rows >= 60 zero-padded)
        #pragma unroll
        for (int mt = 0; mt < 4; ++mt) {
            const int m = mt * 16 + lrow;
            half8 af = {};
            if (m < 60) {
                const float* p = W_fc2 + (size_t)m * 512 + k0;
                const floatx4 f0 = *(const floatx4*)(p);
                const floatx4 f1 = *(const floatx4*)(p + 4);
                const auto p0 = __builtin_amdgcn_cvt_pkrtz(f0[0], f0[1]);
                const auto p1 = __builtin_amdgcn_cvt_pkrtz(f0[2], f0[3]);
                const auto p2 = __builtin_amdgcn_cvt_pkrtz(f1[0], f1[1]);
                const auto p3 = __builtin_amdgcn_cvt_pkrtz(f1[2], f1[3]);
                af[0] = (h16)p0[0]; af[1] = (h16)p0[1]; af[2] = (h16)p1[0]; af[3] = (h16)p1[1];
                af[4] = (h16)p2[0]; af[5] = (h16)p2[1]; af[6] = (h16)p3[0]; af[7] = (h16)p3[1];
            }
            acc[mt] = __builtin_amdgcn_mfma_f32_16x16x32_f16(af, bf, acc[mt], 0, 0, 0);
        }
    }

    // D[row = mt*16 + lgrp*4 + r][col = j0 + lrow]
    #pragma unroll
    for (int mt = 0; mt < 4; ++mt)
        #pragma unroll
        for (int r = 0; r < 4; ++r) {
            const int m = mt * 16 + lgrp * 4 + r;
            if (m < 60) Wc[(size_t)m * NB_FC1 + j0 + lrow] = (h16)acc[mt][r];
        }
}

// bc = W_fc2 @ b_fc1 + b_fc2   [60] fp32
__global__ void bc_kernel(const float* __restrict__ W_fc2, const float* __restrict__ b_fc1,
                          const float* __restrict__ b_fc2, float* __restrict__ bc)
{
    const int m = blockIdx.x, t = threadIdx.x;
    float p = W_fc2[m * 512 + t] * b_fc1[t] + W_fc2[m * 512 + 256 + t] * b_fc1[256 + t];
    #pragma unroll
    for (int off = 1; off < 64; off <<= 1) p += __shfl_xor(p, off);
    __shared__ float sred[4];
    if ((t & 63) == 0) sred[t >> 6] = p;
    __syncthreads();
    if (t == 0) bc[m] = sred[0] + sred[1] + sred[2] + sred[3] + b_fc2[m];
}

// ---------------------------------------------------------------------------
// out[B,60] = h2flat[B,7680] @ Wc^T + bc.
// ---------------------------------------------------------------------------
__global__ __launch_bounds__(256, 2)
void fc_kernel(const h16* __restrict__ h2,
               const h16* __restrict__ Wc,
               const float* __restrict__ bcv,
               float* __restrict__ out)
{
    __shared__ float red[4][4][16][16];   // [wave][q][row][col]
    const int tid = threadIdx.x;
    const int w = tid >> 6, lane = tid & 63, lrow = lane & 15, lgrp = lane >> 4;
    const size_t base_row = (size_t)blockIdx.x * 16;

    floatx4 acc[4];
    #pragma unroll
    for (int q = 0; q < 4; ++q) acc[q] = floatx4{0.f, 0.f, 0.f, 0.f};

    const h16* arow = h2 + (base_row + lrow) * NB_FC1;
    for (int i = 0; i < 60; ++i) {
        const int kt = w * 60 + i;
        const int k0 = kt * 32 + lgrp * 8;
        const half8 a = *(const half8*)(arow + k0);
        #pragma unroll
        for (int q = 0; q < 4; ++q) {
            const int n = q * 16 + lrow;
            half8 b = 0;
            if (n < 60) b = *(const half8*)(Wc + (size_t)n * NB_FC1 + k0);
            acc[q] = __builtin_amdgcn_mfma_f32_16x16x32_f16(a, b, acc[q], 0, 0, 0);
        }
    }
    #pragma unroll
    for (int q = 0; q < 4; ++q)
        #pragma unroll
        for (int r = 0; r < 4; ++r)
            red[w][q][lgrp * 4 + r][lrow] = acc[q][r];
    __syncthreads();

    #pragma unroll
    for (int s = 0; s < 4; ++s) {
        const int idx = tid + 256 * s;
        const int row = idx >> 6, col = idx & 63;
        if (col < 60) {
            const int q = col >> 4, cin = col & 15;
            const float v = red[0][q][row][cin] + red[1][q][row][cin]
                          + red[2][q][row][cin] + red[3][q][row][cin];
            out[(base_row + row) * 60 + col] = v + bcv[col];
        }
    }
}

extern "C" void kernel_launch(void* const* d_in, const int* in_sizes, int n_in,
                              void* d_out, int out_size, void* d_ws, size_t ws_size,
                              hipStream_t stream)
{
    const float* X      = (const float*)d_in[0];
    const float* W_ih1  = (const float*)d_in[1];
    const float* W_hh1  = (const float*)d_in[2];
    const float* b_ih1  = (const float*)d_in[3];
    const float* b_hh1  = (const float*)d_in[4];
    const float* W_ih2  = (const float*)d_in[5];
    const float* W_hh2  = (const float*)d_in[6];
    const float* b_ih2  = (const float*)d_in[7];
    const float* b_hh2  = (const float*)d_in[8];
    const float* W_fc1  = (const float*)d_in[9];
    const float* b_fc1  = (const float*)d_in[10];
    const float* W_fc2  = (const float*)d_in[11];
    const float* b_fc2  = (const float*)d_in[12];

    // workspace layout: h1 (63MB fp16) | h2 (63MB fp16) | Wc (0.92MB fp16) | bc
    h16* h1 = (h16*)d_ws;
    h16* h2 = h1 + (size_t)4096 * NB_FC1;
    h16* Wc = h2 + (size_t)4096 * NB_FC1;
    float* bc = (float*)(Wc + (size_t)60 * NB_FC1);

    wc_kernel<<<120, 256, 0, stream>>>(W_fc1, W_fc2, Wc);
    bc_kernel<<<60, 256, 0, stream>>>(W_fc2, b_fc1, b_fc2, bc);
    lstm_layer<64,  true ><<<256, 512, 0, stream>>>((const void*)X,  W_ih1, W_hh1, b_ih1, b_hh1, h1);
    lstm_layer<128, false><<<256, 512, 0, stream>>>((const void*)h1, W_ih2, W_hh2, b_ih2, b_hh2, h2);
    fc_kernel<<<256, 256, 0, stream>>>(h2, Wc, bc, (float*)d_out);
}